// Round 1
// 13911.101 us; speedup vs baseline: 1.1330x; 1.1330x over previous
//
#include <hip/hip_runtime.h>
#include <stdint.h>

// DMLSTM on MI355X.
// Phase 0: transpose W fp32[1024][2560] -> Wt f16[2560][1024] (n-major, k contiguous)
// Phase 1: Zx = X @ Wx + b  (big f16-MFMA GEMM, parallel, stored f16 in ws)
// Phase 2: persistent recurrent kernel: 4 batch-groups x 64 CUs; W_h slice in LDS;
//          per-step sync via SELF-TAGGED payload words (tag16|h16) in LIC,
//          double-buffered by step parity. No flags, no poll loop, no vmcnt drain.

typedef _Float16 h8 __attribute__((ext_vector_type(8)));
typedef _Float16 h4v __attribute__((ext_vector_type(4)));
typedef float f4 __attribute__((ext_vector_type(4)));

#define SCOPE_AGENT __HIP_MEMORY_SCOPE_AGENT

__device__ __forceinline__ float sigf(float x) {
  x = fminf(fmaxf(x, -40.f), 40.f);
  return 1.f / (1.f + __expf(-x));
}
__device__ __forceinline__ float tanh_f(float x) {
  x = fminf(fmaxf(x, -20.f), 20.f);
  const float e = __expf(2.f * x);
  return (e - 1.f) / (e + 1.f);
}

// ---------------- Phase 0: W -> Wt (f16, transposed) ----------------
__global__ __launch_bounds__(256) void k_wt(const float* __restrict__ W,
                                            _Float16* __restrict__ Wt) {
  __shared__ __align__(16) _Float16 tl[64][68];
  const int bk = blockIdx.x & 15;   // 1024/64 = 16 tiles in k
  const int bn = blockIdx.x >> 4;   // 2560/64 = 40 tiles in n
  const int t = threadIdx.x;
  {
    const int r = t >> 2, c4 = t & 3;
    const float4* s4 = (const float4*)(W + (size_t)(bk * 64 + r) * 2560 + bn * 64 + c4 * 16);
#pragma unroll
    for (int i = 0; i < 4; i++) {
      float4 v = s4[i];
      tl[r][c4 * 16 + i * 4 + 0] = (_Float16)v.x;
      tl[r][c4 * 16 + i * 4 + 1] = (_Float16)v.y;
      tl[r][c4 * 16 + i * 4 + 2] = (_Float16)v.z;
      tl[r][c4 * 16 + i * 4 + 3] = (_Float16)v.w;
    }
  }
  __syncthreads();
  {
    const int nr = t >> 2, kk = (t & 3) * 16;
    h8 o0, o1;
#pragma unroll
    for (int i = 0; i < 8; i++) {
      o0[i] = tl[kk + i][nr];
      o1[i] = tl[kk + 8 + i][nr];
    }
    _Float16* dst = Wt + (size_t)(bn * 64 + nr) * 1024 + bk * 64 + kk;
    *(h8*)dst = o0;
    *(h8*)(dst + 8) = o1;
  }
}

// ---------------- Phase 1: Zx = X @ Wx + b ----------------
__global__ __launch_bounds__(256) void k_zx(const float* __restrict__ X,
                                            const _Float16* __restrict__ Wt,
                                            const float* __restrict__ bias,
                                            _Float16* __restrict__ Zx,
                                            int s_base, int CS) {
  __shared__ __align__(16) _Float16 As[128][72];
  __shared__ __align__(16) _Float16 Bs[128][72];
  const int bid = blockIdx.x;
  const int nblk = bid % 20;        // 2560/128
  const int mblk = bid / 20;        // n-inner ordering -> concurrent blocks share X stripe
  const int tilesPerB = CS >> 7;
  const int b = mblk / tilesPerB;
  const int s0 = (mblk - b * tilesPerB) << 7;
  const int t = threadIdx.x;
  const int wid = t >> 6, lane = t & 63;
  const int wr = wid >> 1, wc = wid & 1;
  const int lr = (lane >> 4) * 4, lc = lane & 15;
  const int koff = (lane >> 4) * 8;

  const f4 zero4 = {0.f, 0.f, 0.f, 0.f};
  f4 acc[4][4];
#pragma unroll
  for (int i = 0; i < 4; i++)
#pragma unroll
    for (int j = 0; j < 4; j++) acc[i][j] = zero4;

  const float* Xb = X + ((size_t)b * 2048 + (size_t)(s_base + s0)) * 512;
  const _Float16* Bb = Wt + (size_t)nblk * 128 * 1024;
  const int rA = t >> 1, hf = t & 1;

  for (int k0 = 0; k0 < 512; k0 += 64) {
    const float4* s4 = (const float4*)(Xb + (size_t)rA * 512 + k0 + hf * 32);
#pragma unroll
    for (int i = 0; i < 8; i++) {
      float4 v = s4[i];
      h4v o = {(_Float16)v.x, (_Float16)v.y, (_Float16)v.z, (_Float16)v.w};
      *(h4v*)&As[rA][hf * 32 + i * 4] = o;
    }
    const h8* bs = (const h8*)(Bb + (size_t)rA * 1024 + k0 + hf * 32);
#pragma unroll
    for (int i = 0; i < 4; i++) *(h8*)&Bs[rA][hf * 32 + i * 8] = bs[i];
    __syncthreads();
#pragma unroll
    for (int kk = 0; kk < 2; kk++) {
      h8 af[4], bf[4];
      const int kr = kk * 32 + koff;
#pragma unroll
      for (int i = 0; i < 4; i++) af[i] = *(const h8*)&As[wr * 64 + i * 16 + lc][kr];
#pragma unroll
      for (int j = 0; j < 4; j++) bf[j] = *(const h8*)&Bs[wc * 64 + j * 16 + lc][kr];
#pragma unroll
      for (int i = 0; i < 4; i++)
#pragma unroll
        for (int j = 0; j < 4; j++)
          acc[i][j] = __builtin_amdgcn_mfma_f32_16x16x32_f16(af[i], bf[j], acc[i][j], 0, 0, 0);
    }
    __syncthreads();
  }
#pragma unroll
  for (int j = 0; j < 4; j++) {
    const int col = nblk * 128 + wc * 64 + j * 16 + lc;
    const float bc = bias[col];
#pragma unroll
    for (int i = 0; i < 4; i++) {
#pragma unroll
      for (int r = 0; r < 4; r++) {
        const int srow = s0 + wr * 64 + i * 16 + lr + r;
        Zx[((size_t)b * CS + srow) * 2560 + col] = (_Float16)(acc[i][j][r] + bc);
      }
    }
  }
}

// ---------------- Phase 2: persistent recurrence ----------------
// grid = 256 blocks x 256 thr. grp = bid>>6 owns batches [grp*16, grp*16+16).
// ci XCD-swizzled so adjacent H-columns land on the same XCD (Zx/Y L2 locality).
// hbuf word = (tag16 << 16) | h_f16_bits ; tag = global_step + 1 ; 2 buffers by parity.
__global__ __launch_bounds__(256) void k_rec(
    const _Float16* __restrict__ Zx, const _Float16* __restrict__ Wt,
    float* __restrict__ Y, uint32_t* __restrict__ hbuf,
    _Float16* __restrict__ hstate, float* __restrict__ cstate,
    int s_base, int CS) {
  __shared__ __align__(16) _Float16 WsT[40][520];  // [local col][k] (k of h-part)
  __shared__ __align__(16) _Float16 hs[16][520];   // staged h(t) f16
  __shared__ __align__(16) float zsh[16][40];      // z slice fp32
  __shared__ __align__(16) _Float16 zxs[16][40];   // Zx slice for step t
  __shared__ __align__(16) float cbuf[128];        // c state [m][j]

  const int bid = blockIdx.x;
  const int grp = bid >> 6;
  const int ci = ((bid & 7) << 3) | ((bid >> 3) & 7);  // XCD-aware column-owner swizzle
  const int tid = threadIdx.x;
  const int wid = tid >> 6, lane = tid & 63;
  const int hbase = ci * 8;

  // load W_h slice once: WsT[g*8+j][k] = Wt[g*512+hbase+j][512+k]
#pragma unroll
  for (int i = 0; i < 10; i++) {
    const int idx = i * 256 + tid;
    const int lcw = idx >> 6;   // 0..39
    const int ch = idx & 63;    // 8-f16 chunk
    const int g = lcw >> 3, j = lcw & 7;
    const h8* src = (const h8*)(Wt + (size_t)(g * 512 + hbase + j) * 1024 + 512 + ch * 8);
    *(h8*)&WsT[lcw][ch * 8] = *src;
  }
  if (tid < 128) {
    cbuf[tid] = cstate[(grp * 64 + ci) * 128 + tid];
    // publish h(s_base) tagged into buffer (s_base & 1)
    const int m = tid >> 3, j = tid & 7;
    _Float16 hv = hstate[(size_t)(grp * 16 + m) * 512 + hbase + j];
    uint16_t hb;
    __builtin_memcpy(&hb, &hv, 2);
    const uint32_t v = ((uint32_t)(s_base + 1) << 16) | (uint32_t)hb;
    __hip_atomic_store(&hbuf[((size_t)((s_base & 1) * 4 + grp) * 16 + m) * 512 + hbase + j],
                       v, __ATOMIC_RELAXED, SCOPE_AGENT);
  }
  __syncthreads();

  uint32_t* hs32 = (uint32_t*)&hs[0][0];

  for (int t = 0; t < CS; t++) {
    const int G = s_base + t;
    const uint32_t tag = (uint32_t)(G + 1);
    // wave 3: prefetch this step's Zx slice (independent of h)
    if (wid == 3) {
      for (int c = lane; c < 80; c += 64) {
        const int m = c / 5, g = c % 5;
        const h8* src =
            (const h8*)(Zx + ((size_t)(grp * 16 + m) * CS + t) * 2560 + g * 512 + hbase);
        *(h8*)&zxs[m][g * 8] = *src;
      }
    }
    // stage h(t): all 256 threads read tagged u64 pairs, spin-on-data, write LDS
    {
      const uint64_t* src =
          (const uint64_t*)(hbuf + (size_t)((G & 1) * 4 + grp) * 16 * 512);
      uint64_t w[16];
#pragma unroll
      for (int i = 0; i < 16; i++)
        w[i] = __hip_atomic_load(&src[i * 256 + tid], __ATOMIC_RELAXED, SCOPE_AGENT);
#pragma unroll
      for (int i = 0; i < 16; i++) {
        while ((((uint32_t)w[i] >> 16) != tag) |
               (((uint32_t)(w[i] >> 48)) != tag))
          w[i] = __hip_atomic_load(&src[i * 256 + tid], __ATOMIC_RELAXED, SCOPE_AGENT);
        hs32[i * 260 + tid] =
            ((uint32_t)w[i] & 0xffffu) | (((uint32_t)(w[i] >> 32) & 0xffffu) << 16);
      }
    }
    __syncthreads();
    // z = h @ Wh (+Zx): waves 0..2 each own one 16-col MFMA tile (cols 40..47 garbage)
    if (wid < 3) {
      f4 acc = {0.f, 0.f, 0.f, 0.f};
      const int nloc = wid * 16 + (lane & 15);
      const int wrow = nloc < 40 ? nloc : 39;
      const int koff = (lane >> 4) * 8;
#pragma unroll
      for (int ks = 0; ks < 16; ks++) {
        const h8 a = *(const h8*)&hs[lane & 15][ks * 32 + koff];
        const h8 bb = *(const h8*)&WsT[wrow][ks * 32 + koff];
        acc = __builtin_amdgcn_mfma_f32_16x16x32_f16(a, bb, acc, 0, 0, 0);
      }
      if (nloc < 40) {
        const int rb = (lane >> 4) * 4;
#pragma unroll
        for (int r = 0; r < 4; r++)
          zsh[rb + r][nloc] = acc[r] + (float)zxs[rb + r][nloc];
      }
    }
    __syncthreads();
    // gates + state update + DIRECT tagged publish (no extra barrier, no drain)
    if (tid < 128) {
      const int m = tid >> 3, j = tid & 7;
      const float zi = zsh[m][j], zf = zsh[m][8 + j], zo = zsh[m][16 + j];
      const float zc = zsh[m][24 + j], zd = zsh[m][32 + j];
      const float ig = sigf(zi), fg = sigf(zf), og = sigf(zo);
      const float c0 = cbuf[tid];
      const float cp = fg * c0 + ig * tanh_f(zc);
      const float dg = tanh_f(zd);
      const float cn = cp + dg * (cp - c0);
      const float hv = og * tanh_f(cn);
      cbuf[tid] = cn;
      const _Float16 hfv = (_Float16)hv;
      uint16_t hb;
      __builtin_memcpy(&hb, &hfv, 2);
      const uint32_t v = ((uint32_t)(G + 2) << 16) | (uint32_t)hb;
      __hip_atomic_store(
          &hbuf[((size_t)(((G + 1) & 1) * 4 + grp) * 16 + m) * 512 + hbase + j], v,
          __ATOMIC_RELAXED, SCOPE_AGENT);
      asm volatile("" ::: "memory");  // keep publish ahead of Y store / next staging
      Y[((size_t)(grp * 16 + m) * 2048 + (size_t)G) * 512 + hbase + j] = hv;
      if (t == CS - 1) {
        cstate[(grp * 64 + ci) * 128 + tid] = cn;
        hstate[(size_t)(grp * 16 + m) * 512 + hbase + j] = hfv;
      }
    }
  }
}

extern "C" void kernel_launch(void* const* d_in, const int* in_sizes, int n_in,
                              void* d_out, int out_size, void* d_ws, size_t ws_size,
                              hipStream_t stream) {
  const float* X = (const float*)d_in[0];
  const float* W = (const float*)d_in[1];
  const float* bias = (const float*)d_in[2];
  float* Y = (float*)d_out;
  char* ws = (char*)d_ws;

  const size_t szWt = (size_t)2560 * 1024 * 2;  // 5.24 MB
  // choose largest S-chunk whose Zx ring fits in ws (slack covers hbuf/hstate/cstate)
  int CS = 128;
  for (int c = 2048; c >= 128; c >>= 1) {
    const size_t need = szWt + (size_t)64 * c * 2560 * 2 + 512 * 1024;
    if (need <= ws_size) { CS = c; break; }
  }
  const size_t offZx = szWt;
  const size_t szZx = (size_t)64 * CS * 2560 * 2;
  const size_t offHbuf = offZx + szZx;
  const size_t szHbuf = (size_t)2 * 4 * 16 * 512 * 4;  // 262144 (tagged, dbuf)
  const size_t offHst = offHbuf + szHbuf;
  const size_t szHst = (size_t)4 * 16 * 512 * 2;       // 65536
  const size_t offCst = offHst + szHst;
  const size_t szCst = (size_t)4 * 64 * 128 * 4;       // 131072

  _Float16* Wt = (_Float16*)(ws + 0);
  _Float16* Zx = (_Float16*)(ws + offZx);
  uint32_t* hbuf = (uint32_t*)(ws + offHbuf);
  _Float16* hstate = (_Float16*)(ws + offHst);
  float* cstate = (float*)(ws + offCst);

  k_wt<<<640, 256, 0, stream>>>(W, Wt);
  // zero tags + h(0) + c(0) once per launch (tag 0 never matches any expected tag >= 1)
  (void)hipMemsetAsync(ws + offHbuf, 0, szHbuf + szHst + szCst, stream);

  const int nch = 2048 / CS;
  for (int ch = 0; ch < nch; ch++) {
    const int sb = ch * CS;
    k_zx<<<CS * 10, 256, 0, stream>>>(X, Wt, bias, Zx, sb, CS);
    k_rec<<<256, 256, 0, stream>>>(Zx, Wt, Y, hbuf, hstate, cstate, sb, CS);
  }
  (void)in_sizes; (void)n_in; (void)out_size;
}